// Round 1
// baseline (4918.150 us; speedup 1.0000x reference)
//
#include <hip/hip_runtime.h>
#include <cstdint>

#define HIDDEN 384
#define NSUPER 2048
#define MAXDEG 32
#define SRC_LD 388   // padded LDS stride in floats (16B-aligned: 388*4=1552)

// Detect whether neighbor_mask arrived as uint8 bytes (numpy bool memory) or
// as int32 words. Reads first 16384 words = 65536 bytes, safe under both
// layouts (uint8 buffer is exactly 65536 bytes). uint8 layout produces words
// like 0x01010101 (expected degree ~38 => most rows fully true); int32 layout
// has every word in {0,1}.
__global__ void detect_mask_fmt(const unsigned int* __restrict__ w,
                                int* __restrict__ flag) {
    __shared__ int s;
    if (threadIdx.x == 0) s = 0;
    __syncthreads();
    int bad = 0;
    for (int i = threadIdx.x; i < 16384; i += blockDim.x)
        if (w[i] > 1u) bad = 1;
    if (bad) s = 1;           // benign same-value race
    __syncthreads();
    if (threadIdx.x == 0) *flag = s;   // 1 => uint8 layout, 0 => int32 layout
}

// One block per supernode. 128 threads; thread t owns output columns
// {t, 128+t, 256+t} through every stage (no cross-thread reductions needed).
__global__ __launch_bounds__(128)
void upt_supernode_kernel(
    const float* __restrict__ pos,
    const float* __restrict__ feat,
    const int*   __restrict__ sn_idx,
    const int*   __restrict__ nbr_idx,
    const void*  __restrict__ mask_raw,
    const int*   __restrict__ mask_fmt,
    const float* __restrict__ W_in,
    const float* __restrict__ b_in,
    const float* __restrict__ W1,
    const float* __restrict__ b1,
    const float* __restrict__ W2,
    const float* __restrict__ b2,
    const float* __restrict__ Wp,
    const float* __restrict__ bp,
    float* __restrict__ out)
{
    __shared__ float SRC[MAXDEG][SRC_LD];  // embeds, then reused for gelu output G
    __shared__ float snx[HIDDEN];
    __shared__ float freqs[64];
    __shared__ float aggs[HIDDEN];
    __shared__ int   nidx[MAXDEG];
    __shared__ float mval[MAXDEG];

    const int sb = blockIdx.x;
    const int t  = threadIdx.x;

    if (t < 64) {
        // freq_j = 10000^(-j/64) = 2^(-j * log2(10000)/64)
        freqs[t] = exp2f(-(float)t * 0.2076205059304601f);
    }
    if (t >= 64 && t < 64 + MAXDEG) {
        int n = t - 64;
        nidx[n] = nbr_idx[sb * MAXDEG + n];
        int fmt = *mask_fmt;
        int mv = fmt ? (int)((const unsigned char*)mask_raw)[sb * MAXDEG + n]
                     : ((const int*)mask_raw)[sb * MAXDEG + n];
        mval[n] = mv ? 1.0f : 0.0f;
    }
    __syncthreads();

    const int snp = sn_idx[sb];

    // ---- embeddings: x = sincos(pos) + feat @ W_in + b_in ----
    // dim layout: for coord c in {0,1,2}: [sin(c*f0..f63), cos(c*f0..f63)]
    const float fr = freqs[t & 63];
    for (int p = 0; p < MAXDEG + 1; ++p) {
        const int pi = (p < MAXDEG) ? nidx[p] : snp;
        const float c0 = pos[pi*3+0], c1 = pos[pi*3+1], c2 = pos[pi*3+2];
        const float f0 = feat[pi*3+0], f1 = feat[pi*3+1], f2 = feat[pi*3+2];
        #pragma unroll
        for (int cc = 0; cc < 3; ++cc) {
            const int dim = cc*128 + t;
            const float coord = (cc==0) ? c0 : ((cc==1) ? c1 : c2);
            const float a = coord * fr;
            const float base = (t < 64) ? sinf(a) : cosf(a);
            const float v = base
                + f0*W_in[0*HIDDEN+dim] + f1*W_in[1*HIDDEN+dim] + f2*W_in[2*HIDDEN+dim]
                + b_in[dim];
            if (p < MAXDEG) SRC[p][dim] = v; else snx[dim] = v;
        }
    }
    __syncthreads();

    // ---- layer 1: h = [src, dst];  y1 = h @ W1 + b1 ----
    // dst part (rows 384..767 of W1) is identical for all 32 neighbors:
    float dstT[3] = {0.f, 0.f, 0.f};
    for (int d = 0; d < HIDDEN; d += 4) {
        const float4 h = *(const float4*)&snx[d];
        #pragma unroll
        for (int cc = 0; cc < 3; ++cc) {
            const int col = cc*128 + t;
            const float* w = &W1[(HIDDEN + d)*HIDDEN + col];
            dstT[cc] += h.x*w[0] + h.y*w[HIDDEN] + h.z*w[2*HIDDEN] + h.w*w[3*HIDDEN];
        }
    }

    float acc[3][MAXDEG];
    #pragma unroll
    for (int cc = 0; cc < 3; ++cc)
        #pragma unroll
        for (int n = 0; n < MAXDEG; ++n) acc[cc][n] = 0.f;

    for (int d = 0; d < HIDDEN; d += 4) {
        float w0[3], w1[3], w2[3], w3[3];
        #pragma unroll
        for (int cc = 0; cc < 3; ++cc) {
            const int col = cc*128 + t;
            const float* w = &W1[d*HIDDEN + col];
            w0[cc]=w[0]; w1[cc]=w[HIDDEN]; w2[cc]=w[2*HIDDEN]; w3[cc]=w[3*HIDDEN];
        }
        #pragma unroll 8
        for (int n = 0; n < MAXDEG; ++n) {
            const float4 h = *(const float4*)&SRC[n][d];  // broadcast read
            #pragma unroll
            for (int cc = 0; cc < 3; ++cc)
                acc[cc][n] += h.x*w0[cc] + h.y*w1[cc] + h.z*w2[cc] + h.w*w3[cc];
        }
    }
    __syncthreads();   // everyone done reading SRC embeds

    // gelu (exact) and write G into SRC buffer
    #pragma unroll
    for (int cc = 0; cc < 3; ++cc) {
        const int col = cc*128 + t;
        const float bb = b1[col] + dstT[cc];
        for (int n = 0; n < MAXDEG; ++n) {
            const float y = acc[cc][n] + bb;
            const float g = 0.5f * y * (1.0f + erff(y * 0.70710678118654752f));
            SRC[n][col] = g;
        }
    }
    __syncthreads();

    // ---- layer 2: y2 = G @ W2 + b2 ----
    #pragma unroll
    for (int cc = 0; cc < 3; ++cc)
        #pragma unroll
        for (int n = 0; n < MAXDEG; ++n) acc[cc][n] = 0.f;

    for (int d = 0; d < HIDDEN; d += 4) {
        float w0[3], w1[3], w2[3], w3[3];
        #pragma unroll
        for (int cc = 0; cc < 3; ++cc) {
            const int col = cc*128 + t;
            const float* w = &W2[d*HIDDEN + col];
            w0[cc]=w[0]; w1[cc]=w[HIDDEN]; w2[cc]=w[2*HIDDEN]; w3[cc]=w[3*HIDDEN];
        }
        #pragma unroll 8
        for (int n = 0; n < MAXDEG; ++n) {
            const float4 g = *(const float4*)&SRC[n][d];
            #pragma unroll
            for (int cc = 0; cc < 3; ++cc)
                acc[cc][n] += g.x*w0[cc] + g.y*w1[cc] + g.z*w2[cc] + g.w*w3[cc];
        }
    }

    // masked mean
    float cnt = 0.f;
    #pragma unroll
    for (int n = 0; n < MAXDEG; ++n) cnt += mval[n];
    const float inv = 1.0f / fmaxf(cnt, 1.0f);

    #pragma unroll
    for (int cc = 0; cc < 3; ++cc) {
        const int col = cc*128 + t;
        const float bb = b2[col];
        float s = 0.f;
        for (int n = 0; n < MAXDEG; ++n) s += mval[n] * (acc[cc][n] + bb);
        aggs[col] = s * inv;
    }
    __syncthreads();

    // ---- projection: out = [agg, sn] @ Wp + bp ----
    #pragma unroll
    for (int cc = 0; cc < 3; ++cc) {
        const int col = cc*128 + t;
        float o = bp[col];
        for (int d = 0; d < HIDDEN; d += 4) {
            const float4 a = *(const float4*)&aggs[d];
            const float* w = &Wp[d*HIDDEN + col];
            o += a.x*w[0] + a.y*w[HIDDEN] + a.z*w[2*HIDDEN] + a.w*w[3*HIDDEN];
        }
        for (int d = 0; d < HIDDEN; d += 4) {
            const float4 a = *(const float4*)&snx[d];
            const float* w = &Wp[(HIDDEN + d)*HIDDEN + col];
            o += a.x*w[0] + a.y*w[HIDDEN] + a.z*w[2*HIDDEN] + a.w*w[3*HIDDEN];
        }
        out[sb*HIDDEN + col] = o;
    }
}

extern "C" void kernel_launch(void* const* d_in, const int* in_sizes, int n_in,
                              void* d_out, int out_size, void* d_ws, size_t ws_size,
                              hipStream_t stream) {
    const float* pos   = (const float*)d_in[0];
    const float* feat  = (const float*)d_in[1];
    const int*   sn    = (const int*)d_in[2];
    const int*   nbr   = (const int*)d_in[3];
    const void*  mask  = d_in[4];
    const float* W_in  = (const float*)d_in[5];
    const float* b_in  = (const float*)d_in[6];
    const float* W1    = (const float*)d_in[7];
    const float* b1    = (const float*)d_in[8];
    const float* W2    = (const float*)d_in[9];
    const float* b2    = (const float*)d_in[10];
    const float* Wp    = (const float*)d_in[11];
    const float* bp    = (const float*)d_in[12];
    float* out = (float*)d_out;
    int* flag = (int*)d_ws;

    hipLaunchKernelGGL(detect_mask_fmt, dim3(1), dim3(256), 0, stream,
                       (const unsigned int*)mask, flag);
    hipLaunchKernelGGL(upt_supernode_kernel, dim3(NSUPER), dim3(128), 0, stream,
                       pos, feat, sn, nbr, mask, flag,
                       W_in, b_in, W1, b1, W2, b2, Wp, bp, out);
}

// Round 2
// 1122.665 us; speedup vs baseline: 4.3808x; 4.3808x over previous
//
#include <hip/hip_runtime.h>
#include <cstdint>

#define HIDDEN 384
#define NSUPER 2048
#define MAXDEG 32
#define SRC_LD 388   // padded LDS stride in floats (16B-aligned: 388*4=1552)

// Detect whether neighbor_mask arrived as uint8 bytes (numpy bool memory) or
// as int32 words. Reads first 16384 words = 65536 bytes, safe under both
// layouts. uint8 layout produces words like 0x01010101; int32 layout has
// every word in {0,1}.
__global__ void detect_mask_fmt(const unsigned int* __restrict__ w,
                                int* __restrict__ flag) {
    __shared__ int s;
    if (threadIdx.x == 0) s = 0;
    __syncthreads();
    int bad = 0;
    for (int i = threadIdx.x; i < 16384; i += blockDim.x)
        if (w[i] > 1u) bad = 1;
    if (bad) s = 1;           // benign same-value race
    __syncthreads();
    if (threadIdx.x == 0) *flag = s;   // 1 => uint8 layout, 0 => int32 layout
}

// One block per supernode. 128 threads; thread t owns output columns
// {t, 128+t, 256+t} through every stage.
// ALL loops indexing acc[][] are FULLY unrolled => register-resident
// accumulators (round-1 had partial unroll => 15 GB of scratch traffic).
__global__ __launch_bounds__(128)
void upt_supernode_kernel(
    const float* __restrict__ pos,
    const float* __restrict__ feat,
    const int*   __restrict__ sn_idx,
    const int*   __restrict__ nbr_idx,
    const void*  __restrict__ mask_raw,
    const int*   __restrict__ mask_fmt,
    const float* __restrict__ W_in,
    const float* __restrict__ b_in,
    const float* __restrict__ W1,
    const float* __restrict__ b1,
    const float* __restrict__ W2,
    const float* __restrict__ b2,
    const float* __restrict__ Wp,
    const float* __restrict__ bp,
    float* __restrict__ out)
{
    __shared__ float SRC[MAXDEG][SRC_LD];  // embeds, then reused for gelu output G
    __shared__ float snx[HIDDEN];
    __shared__ float freqs[64];
    __shared__ float aggs[HIDDEN];
    __shared__ int   nidx[MAXDEG];
    __shared__ float mval[MAXDEG];

    const int sb = blockIdx.x;
    const int t  = threadIdx.x;

    if (t < 64) {
        // freq_j = 10000^(-j/64) = 2^(-j * log2(10000)/64)
        freqs[t] = exp2f(-(float)t * 0.2076205059304601f);
    }
    if (t >= 64 && t < 64 + MAXDEG) {
        int n = t - 64;
        nidx[n] = nbr_idx[sb * MAXDEG + n];
        int fmt = *mask_fmt;
        int mv = fmt ? (int)((const unsigned char*)mask_raw)[sb * MAXDEG + n]
                     : ((const int*)mask_raw)[sb * MAXDEG + n];
        mval[n] = mv ? 1.0f : 0.0f;
    }
    __syncthreads();

    const int snp = sn_idx[sb];

    // ---- embeddings: x = sincos(pos) + feat @ W_in + b_in ----
    const float fr = freqs[t & 63];
    for (int p = 0; p < MAXDEG + 1; ++p) {
        const int pi = (p < MAXDEG) ? nidx[p] : snp;
        const float c0 = pos[pi*3+0], c1 = pos[pi*3+1], c2 = pos[pi*3+2];
        const float f0 = feat[pi*3+0], f1 = feat[pi*3+1], f2 = feat[pi*3+2];
        #pragma unroll
        for (int cc = 0; cc < 3; ++cc) {
            const int dim = cc*128 + t;
            const float coord = (cc==0) ? c0 : ((cc==1) ? c1 : c2);
            const float a = coord * fr;
            const float base = (t < 64) ? sinf(a) : cosf(a);
            const float v = base
                + f0*W_in[0*HIDDEN+dim] + f1*W_in[1*HIDDEN+dim] + f2*W_in[2*HIDDEN+dim]
                + b_in[dim];
            if (p < MAXDEG) SRC[p][dim] = v; else snx[dim] = v;
        }
    }
    __syncthreads();

    // ---- layer 1: h = [src, dst];  y1 = h @ W1 + b1 ----
    // dst part (rows 384..767 of W1) is identical for all 32 neighbors:
    float dstT[3] = {0.f, 0.f, 0.f};
    for (int d = 0; d < HIDDEN; d += 4) {
        const float4 h = *(const float4*)&snx[d];
        #pragma unroll
        for (int cc = 0; cc < 3; ++cc) {
            const int col = cc*128 + t;
            const float* w = &W1[(HIDDEN + d)*HIDDEN + col];
            dstT[cc] += h.x*w[0] + h.y*w[HIDDEN] + h.z*w[2*HIDDEN] + h.w*w[3*HIDDEN];
        }
    }

    float acc[3][MAXDEG];
    #pragma unroll
    for (int cc = 0; cc < 3; ++cc)
        #pragma unroll
        for (int n = 0; n < MAXDEG; ++n) acc[cc][n] = 0.f;

    for (int d = 0; d < HIDDEN; d += 4) {
        float w0[3], w1[3], w2[3], w3[3];
        #pragma unroll
        for (int cc = 0; cc < 3; ++cc) {
            const int col = cc*128 + t;
            const float* w = &W1[d*HIDDEN + col];
            w0[cc]=w[0]; w1[cc]=w[HIDDEN]; w2[cc]=w[2*HIDDEN]; w3[cc]=w[3*HIDDEN];
        }
        #pragma unroll
        for (int n = 0; n < MAXDEG; ++n) {
            const float4 h = *(const float4*)&SRC[n][d];  // broadcast read
            #pragma unroll
            for (int cc = 0; cc < 3; ++cc)
                acc[cc][n] += h.x*w0[cc] + h.y*w1[cc] + h.z*w2[cc] + h.w*w3[cc];
        }
    }
    __syncthreads();   // everyone done reading SRC embeds

    // gelu (exact) and write G into SRC buffer
    #pragma unroll
    for (int cc = 0; cc < 3; ++cc) {
        const int col = cc*128 + t;
        const float bb = b1[col] + dstT[cc];
        #pragma unroll
        for (int n = 0; n < MAXDEG; ++n) {
            const float y = acc[cc][n] + bb;
            const float g = 0.5f * y * (1.0f + erff(y * 0.70710678118654752f));
            SRC[n][col] = g;
        }
    }
    __syncthreads();

    // ---- layer 2: y2 = G @ W2 + b2 ----
    #pragma unroll
    for (int cc = 0; cc < 3; ++cc)
        #pragma unroll
        for (int n = 0; n < MAXDEG; ++n) acc[cc][n] = 0.f;

    for (int d = 0; d < HIDDEN; d += 4) {
        float w0[3], w1[3], w2[3], w3[3];
        #pragma unroll
        for (int cc = 0; cc < 3; ++cc) {
            const int col = cc*128 + t;
            const float* w = &W2[d*HIDDEN + col];
            w0[cc]=w[0]; w1[cc]=w[HIDDEN]; w2[cc]=w[2*HIDDEN]; w3[cc]=w[3*HIDDEN];
        }
        #pragma unroll
        for (int n = 0; n < MAXDEG; ++n) {
            const float4 g = *(const float4*)&SRC[n][d];
            #pragma unroll
            for (int cc = 0; cc < 3; ++cc)
                acc[cc][n] += g.x*w0[cc] + g.y*w1[cc] + g.z*w2[cc] + g.w*w3[cc];
        }
    }

    // masked mean
    float cnt = 0.f;
    #pragma unroll
    for (int n = 0; n < MAXDEG; ++n) cnt += mval[n];
    const float inv = 1.0f / fmaxf(cnt, 1.0f);

    #pragma unroll
    for (int cc = 0; cc < 3; ++cc) {
        const int col = cc*128 + t;
        const float bb = b2[col];
        float s = 0.f;
        #pragma unroll
        for (int n = 0; n < MAXDEG; ++n) s += mval[n] * (acc[cc][n] + bb);
        aggs[col] = s * inv;
    }
    __syncthreads();

    // ---- projection: out = [agg, sn] @ Wp + bp ----
    #pragma unroll
    for (int cc = 0; cc < 3; ++cc) {
        const int col = cc*128 + t;
        float o = bp[col];
        for (int d = 0; d < HIDDEN; d += 4) {
            const float4 a = *(const float4*)&aggs[d];
            const float* w = &Wp[d*HIDDEN + col];
            o += a.x*w[0] + a.y*w[HIDDEN] + a.z*w[2*HIDDEN] + a.w*w[3*HIDDEN];
        }
        for (int d = 0; d < HIDDEN; d += 4) {
            const float4 a = *(const float4*)&snx[d];
            const float* w = &Wp[(HIDDEN + d)*HIDDEN + col];
            o += a.x*w[0] + a.y*w[HIDDEN] + a.z*w[2*HIDDEN] + a.w*w[3*HIDDEN];
        }
        out[sb*HIDDEN + col] = o;
    }
}

extern "C" void kernel_launch(void* const* d_in, const int* in_sizes, int n_in,
                              void* d_out, int out_size, void* d_ws, size_t ws_size,
                              hipStream_t stream) {
    const float* pos   = (const float*)d_in[0];
    const float* feat  = (const float*)d_in[1];
    const int*   sn    = (const int*)d_in[2];
    const int*   nbr   = (const int*)d_in[3];
    const void*  mask  = d_in[4];
    const float* W_in  = (const float*)d_in[5];
    const float* b_in  = (const float*)d_in[6];
    const float* W1    = (const float*)d_in[7];
    const float* b1    = (const float*)d_in[8];
    const float* W2    = (const float*)d_in[9];
    const float* b2    = (const float*)d_in[10];
    const float* Wp    = (const float*)d_in[11];
    const float* bp    = (const float*)d_in[12];
    float* out = (float*)d_out;
    int* flag = (int*)d_ws;

    hipLaunchKernelGGL(detect_mask_fmt, dim3(1), dim3(256), 0, stream,
                       (const unsigned int*)mask, flag);
    hipLaunchKernelGGL(upt_supernode_kernel, dim3(NSUPER), dim3(128), 0, stream,
                       pos, feat, sn, nbr, mask, flag,
                       W_in, b_in, W1, b1, W2, b2, Wp, bp, out);
}

// Round 3
// 274.838 us; speedup vs baseline: 17.8947x; 4.0848x over previous
//
#include <hip/hip_runtime.h>
#include <hip/hip_bf16.h>
#include <cstdint>

#define HIDDEN 384
#define NSUPER 2048
#define MAXDEG 32
#define SROW 392   // padded LDS row stride in shorts (784 B; 196 words %32 = 4 -> spread banks)

typedef __attribute__((ext_vector_type(8))) short bf16x8;
typedef __attribute__((ext_vector_type(4))) float f32x4;

__device__ inline unsigned short f2bf(float f) {
    __hip_bfloat16 h = __float2bfloat16(f);   // RNE
    return *reinterpret_cast<unsigned short*>(&h);
}

// ---- mask format detect (uint8 numpy-bool vs int32) ----
__global__ void detect_mask_fmt(const unsigned int* __restrict__ w,
                                int* __restrict__ flag) {
    __shared__ int s;
    if (threadIdx.x == 0) s = 0;
    __syncthreads();
    int bad = 0;
    for (int i = threadIdx.x; i < 16384; i += blockDim.x)
        if (w[i] > 1u) bad = 1;
    if (bad) s = 1;
    __syncthreads();
    if (threadIdx.x == 0) *flag = s;   // 1 => uint8, 0 => int32
}

// ---- repack a 384x384 fp32 weight block into fragment-major bf16 ----
// frag (kt in [0,12), nt in [0,24)): lane l elem j = W[kt*32 + (l>>4)*8 + j][nt*16 + (l&15)]
// out[((kt*24+nt)*64 + l)*8 + j]. One thread per (frag,lane) = 18432 threads.
__global__ void repack_w(const float* __restrict__ W, unsigned short* __restrict__ out) {
    int idx = blockIdx.x * 256 + threadIdx.x;
    if (idx >= 12 * 24 * 64) return;
    int l    = idx & 63;
    int frag = idx >> 6;
    int nt   = frag % 24;
    int kt   = frag / 24;
    int col  = nt * 16 + (l & 15);
    int k0   = kt * 32 + (l >> 4) * 8;
    unsigned int pk[4];
    #pragma unroll
    for (int j = 0; j < 4; ++j) {
        unsigned int lo = f2bf(W[(k0 + 2 * j) * HIDDEN + col]);
        unsigned int hi = f2bf(W[(k0 + 2 * j + 1) * HIDDEN + col]);
        pk[j] = lo | (hi << 16);
    }
    *reinterpret_cast<uint4*>(&out[(size_t)idx * 8]) =
        *reinterpret_cast<const uint4*>(pk);
}

// ---- main: one block (2 waves) per supernode ----
__global__ __launch_bounds__(128)
void upt_main(
    const float* __restrict__ pos,
    const float* __restrict__ feat,
    const int*   __restrict__ sn_idx,
    const int*   __restrict__ nbr_idx,
    const void*  __restrict__ mask_raw,
    const int*   __restrict__ mask_fmt,
    const float* __restrict__ W_in,
    const float* __restrict__ b_in,
    const float* __restrict__ W1,     // fp32, rows 384..767 used for dst term
    const float* __restrict__ b1,
    const unsigned short* __restrict__ W1f,  // frag-major bf16, rows 0..383
    const unsigned short* __restrict__ W2f,  // frag-major bf16
    const float* __restrict__ b2,
    const float* __restrict__ Wp,
    const float* __restrict__ bp,
    float* __restrict__ out)
{
    __shared__ unsigned short SRCG[MAXDEG][SROW];  // bf16 embeds, reused for gelu out G
    __shared__ float snx[HIDDEN];
    __shared__ float dstv[HIDDEN];                 // dstT + b1
    __shared__ float aggs[HIDDEN];
    __shared__ float freqs[64];
    __shared__ int   nidx[MAXDEG];
    __shared__ float mval[MAXDEG];

    const int sb = blockIdx.x;
    const int t  = threadIdx.x;

    if (t < 64) freqs[t] = exp2f(-(float)t * 0.2076205059304601f); // 10000^(-t/64)
    if (t >= 64 && t < 64 + MAXDEG) {
        int n = t - 64;
        nidx[n] = nbr_idx[sb * MAXDEG + n];
        int fmt = *mask_fmt;
        int mv = fmt ? (int)((const unsigned char*)mask_raw)[sb * MAXDEG + n]
                     : ((const int*)mask_raw)[sb * MAXDEG + n];
        mval[n] = mv ? 1.0f : 0.0f;
    }
    __syncthreads();

    const int snp = sn_idx[sb];

    // ---- phase 1: embeddings -> SRCG (bf16) and snx (fp32) ----
    const float fr = freqs[t & 63];
    for (int p = 0; p < MAXDEG + 1; ++p) {
        const int pi = (p < MAXDEG) ? nidx[p] : snp;
        const float c0 = pos[pi*3+0], c1 = pos[pi*3+1], c2 = pos[pi*3+2];
        const float f0 = feat[pi*3+0], f1 = feat[pi*3+1], f2 = feat[pi*3+2];
        #pragma unroll
        for (int cc = 0; cc < 3; ++cc) {
            const int dim = cc*128 + t;
            const float coord = (cc==0) ? c0 : ((cc==1) ? c1 : c2);
            const float a = coord * fr;
            const float base = (t < 64) ? sinf(a) : cosf(a);
            const float v = base
                + f0*W_in[0*HIDDEN+dim] + f1*W_in[1*HIDDEN+dim] + f2*W_in[2*HIDDEN+dim]
                + b_in[dim];
            if (p < MAXDEG) SRCG[p][dim] = f2bf(v); else snx[dim] = v;
        }
    }
    __syncthreads();

    // ---- phase 2: dst term (fp32): dstv[col] = snx @ W1[384:768, col] + b1[col] ----
    {
        float dstT[3] = {0.f, 0.f, 0.f};
        for (int d = 0; d < HIDDEN; d += 4) {
            const float4 h = *(const float4*)&snx[d];
            #pragma unroll
            for (int cc = 0; cc < 3; ++cc) {
                const int col = cc*128 + t;
                const float* w = &W1[(HIDDEN + d)*HIDDEN + col];
                dstT[cc] += h.x*w[0] + h.y*w[HIDDEN] + h.z*w[2*HIDDEN] + h.w*w[3*HIDDEN];
            }
        }
        #pragma unroll
        for (int cc = 0; cc < 3; ++cc)
            dstv[cc*128 + t] = dstT[cc] + b1[cc*128 + t];
    }
    __syncthreads();

    const int w   = t >> 6;    // wave id (owns cols w*192 .. w*192+191)
    const int l   = t & 63;
    const int lg  = l >> 4;
    const int l15 = l & 15;

    f32x4 acc[12][2];

    // ---- phase 3: layer1 src GEMM via MFMA: y1 = SRC @ W1[0:384] ----
    #pragma unroll
    for (int nt = 0; nt < 12; ++nt) {
        acc[nt][0] = (f32x4){0.f,0.f,0.f,0.f};
        acc[nt][1] = (f32x4){0.f,0.f,0.f,0.f};
    }
    for (int kt = 0; kt < 12; ++kt) {
        bf16x8 a0 = *(const bf16x8*)&SRCG[l15     ][kt*32 + lg*8];
        bf16x8 a1 = *(const bf16x8*)&SRCG[16 + l15][kt*32 + lg*8];
        const unsigned short* bptr = &W1f[(((size_t)kt*24 + w*12)*64 + l)*8];
        #pragma unroll
        for (int nt = 0; nt < 12; ++nt) {
            bf16x8 b = *(const bf16x8*)(bptr + (size_t)nt*64*8);
            acc[nt][0] = __builtin_amdgcn_mfma_f32_16x16x32_bf16(a0, b, acc[nt][0], 0,0,0);
            acc[nt][1] = __builtin_amdgcn_mfma_f32_16x16x32_bf16(a1, b, acc[nt][1], 0,0,0);
        }
    }
    __syncthreads();   // both waves done reading SRCG

    // ---- phase 4: +dst+b1, exact gelu, write G (bf16) into SRCG ----
    #pragma unroll
    for (int nt = 0; nt < 12; ++nt) {
        const int col = w*192 + nt*16 + l15;
        const float dv = dstv[col];
        #pragma unroll
        for (int mt = 0; mt < 2; ++mt) {
            #pragma unroll
            for (int r = 0; r < 4; ++r) {
                const int row = mt*16 + lg*4 + r;
                const float y = acc[nt][mt][r] + dv;
                const float g = 0.5f * y * (1.0f + erff(y * 0.70710678118654752f));
                SRCG[row][col] = f2bf(g);
            }
        }
    }
    __syncthreads();   // G complete

    // ---- phase 5: layer2 GEMM: y2 = G @ W2 ----
    #pragma unroll
    for (int nt = 0; nt < 12; ++nt) {
        acc[nt][0] = (f32x4){0.f,0.f,0.f,0.f};
        acc[nt][1] = (f32x4){0.f,0.f,0.f,0.f};
    }
    for (int kt = 0; kt < 12; ++kt) {
        bf16x8 a0 = *(const bf16x8*)&SRCG[l15     ][kt*32 + lg*8];
        bf16x8 a1 = *(const bf16x8*)&SRCG[16 + l15][kt*32 + lg*8];
        const unsigned short* bptr = &W2f[(((size_t)kt*24 + w*12)*64 + l)*8];
        #pragma unroll
        for (int nt = 0; nt < 12; ++nt) {
            bf16x8 b = *(const bf16x8*)(bptr + (size_t)nt*64*8);
            acc[nt][0] = __builtin_amdgcn_mfma_f32_16x16x32_bf16(a0, b, acc[nt][0], 0,0,0);
            acc[nt][1] = __builtin_amdgcn_mfma_f32_16x16x32_bf16(a1, b, acc[nt][1], 0,0,0);
        }
    }

    // ---- phase 6: masked mean across the 32 edges (rows) ----
    {
        float cnt = 0.f;
        #pragma unroll
        for (int n = 0; n < MAXDEG; ++n) cnt += mval[n];
        const float nz  = (cnt > 0.f) ? 1.f : 0.f;
        const float inv = 1.0f / fmaxf(cnt, 1.0f);

        float mv[8];
        #pragma unroll
        for (int mt = 0; mt < 2; ++mt)
            #pragma unroll
            for (int r = 0; r < 4; ++r)
                mv[mt*4 + r] = mval[mt*16 + lg*4 + r];

        #pragma unroll
        for (int nt = 0; nt < 12; ++nt) {
            const int col = w*192 + nt*16 + l15;
            float s = 0.f;
            #pragma unroll
            for (int mt = 0; mt < 2; ++mt)
                #pragma unroll
                for (int r = 0; r < 4; ++r)
                    s += mv[mt*4 + r] * acc[nt][mt][r];
            s += __shfl_xor(s, 16);
            s += __shfl_xor(s, 32);
            if (lg == 0) aggs[col] = s * inv + b2[col] * nz;
        }
    }
    __syncthreads();

    // ---- phase 7: projection (fp32): out = [agg, sn] @ Wp + bp ----
    #pragma unroll
    for (int cc = 0; cc < 3; ++cc) {
        const int col = cc*128 + t;
        float o = bp[col];
        for (int d = 0; d < HIDDEN; d += 4) {
            const float4 a = *(const float4*)&aggs[d];
            const float* wp_ = &Wp[d*HIDDEN + col];
            o += a.x*wp_[0] + a.y*wp_[HIDDEN] + a.z*wp_[2*HIDDEN] + a.w*wp_[3*HIDDEN];
        }
        for (int d = 0; d < HIDDEN; d += 4) {
            const float4 a = *(const float4*)&snx[d];
            const float* wp_ = &Wp[(HIDDEN + d)*HIDDEN + col];
            o += a.x*wp_[0] + a.y*wp_[HIDDEN] + a.z*wp_[2*HIDDEN] + a.w*wp_[3*HIDDEN];
        }
        out[sb*HIDDEN + col] = o;
    }
}

extern "C" void kernel_launch(void* const* d_in, const int* in_sizes, int n_in,
                              void* d_out, int out_size, void* d_ws, size_t ws_size,
                              hipStream_t stream) {
    const float* pos   = (const float*)d_in[0];
    const float* feat  = (const float*)d_in[1];
    const int*   sn    = (const int*)d_in[2];
    const int*   nbr   = (const int*)d_in[3];
    const void*  mask  = d_in[4];
    const float* W_in  = (const float*)d_in[5];
    const float* b_in  = (const float*)d_in[6];
    const float* W1    = (const float*)d_in[7];
    const float* b1    = (const float*)d_in[8];
    const float* W2    = (const float*)d_in[9];
    const float* b2    = (const float*)d_in[10];
    const float* Wp    = (const float*)d_in[11];
    const float* bp    = (const float*)d_in[12];
    float* out = (float*)d_out;

    int* flag = (int*)d_ws;
    unsigned short* w1f = (unsigned short*)((char*)d_ws + 1024);
    unsigned short* w2f = w1f + (size_t)12*24*64*8;   // +294912 B

    hipLaunchKernelGGL(detect_mask_fmt, dim3(1), dim3(256), 0, stream,
                       (const unsigned int*)mask, flag);
    hipLaunchKernelGGL(repack_w, dim3((12*24*64 + 255)/256), dim3(256), 0, stream, W1, w1f);
    hipLaunchKernelGGL(repack_w, dim3((12*24*64 + 255)/256), dim3(256), 0, stream, W2, w2f);
    hipLaunchKernelGGL(upt_main, dim3(NSUPER), dim3(128), 0, stream,
                       pos, feat, sn, nbr, mask, flag,
                       W_in, b_in, W1, b1, w1f, w2f, b2, Wp, bp, out);
}

// Round 4
// 171.651 us; speedup vs baseline: 28.6521x; 1.6011x over previous
//
#include <hip/hip_runtime.h>
#include <hip/hip_bf16.h>
#include <cstdint>

#define HIDDEN 384
#define NSUPER 2048
#define MAXDEG 32
#define BM 128      // edge rows per k_mlp block = 4 supernodes

typedef __attribute__((ext_vector_type(8))) short bf16x8;
typedef __attribute__((ext_vector_type(4))) float f32x4;

__device__ inline unsigned short f2bf(float f) {
    __hip_bfloat16 h = __float2bfloat16(f);   // RNE
    return *reinterpret_cast<unsigned short*>(&h);
}
__device__ inline bf16x8 pack8(const float* v) {
    union { bf16x8 v8; unsigned short u[8]; } u;
    #pragma unroll
    for (int i = 0; i < 8; ++i) u.u[i] = f2bf(v[i]);
    return u.v8;
}

// ---- mask format detect (uint8 numpy-bool vs int32) ----
__global__ void detect_mask_fmt(const unsigned int* __restrict__ w,
                                int* __restrict__ flag) {
    __shared__ int s;
    if (threadIdx.x == 0) s = 0;
    __syncthreads();
    int bad = 0;
    for (int i = threadIdx.x; i < 16384; i += blockDim.x)
        if (w[i] > 1u) bad = 1;
    if (bad) s = 1;
    __syncthreads();
    if (threadIdx.x == 0) *flag = s;   // 1 => uint8, 0 => int32
}

// ---- repack a 384x384 fp32 weight block into fragment-major bf16 ----
// frag (kt,nt): lane l elem j = W[kt*32 + (l>>4)*8 + j][nt*16 + (l&15)]
__global__ void repack_w(const float* __restrict__ W, unsigned short* __restrict__ out) {
    int idx = blockIdx.x * 256 + threadIdx.x;
    if (idx >= 12 * 24 * 64) return;
    int l    = idx & 63;
    int frag = idx >> 6;
    int nt   = frag % 24;
    int kt   = frag / 24;
    int col  = nt * 16 + (l & 15);
    int k0   = kt * 32 + (l >> 4) * 8;
    unsigned int pk[4];
    #pragma unroll
    for (int j = 0; j < 4; ++j) {
        unsigned int lo = f2bf(W[(k0 + 2 * j) * HIDDEN + col]);
        unsigned int hi = f2bf(W[(k0 + 2 * j + 1) * HIDDEN + col]);
        pk[j] = lo | (hi << 16);
    }
    *reinterpret_cast<uint4*>(&out[(size_t)idx * 8]) =
        *reinterpret_cast<const uint4*>(pk);
}

// ---- supernode embeddings: snx[2048][384] fp32 ----
__global__ __launch_bounds__(128)
void k_snx(const float* __restrict__ pos, const float* __restrict__ feat,
           const int* __restrict__ sn_idx,
           const float* __restrict__ W_in, const float* __restrict__ b_in,
           float* __restrict__ snx) {
    const int sb = blockIdx.x, t = threadIdx.x;
    const int pi = sn_idx[sb];
    const float c[3] = {pos[pi*3], pos[pi*3+1], pos[pi*3+2]};
    const float f[3] = {feat[pi*3], feat[pi*3+1], feat[pi*3+2]};
    const float fr = exp2f(-(float)(t & 63) * 0.2076205059304601f);
    #pragma unroll
    for (int cc = 0; cc < 3; ++cc) {
        const int dim = cc*128 + t;
        const float a = c[cc] * fr;
        const float base = (t < 64) ? __sinf(a) : __cosf(a);
        snx[sb*HIDDEN + dim] = base + f[0]*W_in[dim] + f[1]*W_in[HIDDEN+dim]
                             + f[2]*W_in[2*HIDDEN+dim] + b_in[dim];
    }
}

// ---- dstv[2048][384] = bf16(snx) @ W1dst + b1 ----
__global__ __launch_bounds__(256)
void k_dstv(const float* __restrict__ snx, const unsigned short* __restrict__ Wf,
            const float* __restrict__ b1, float* __restrict__ dstv) {
    const int t = threadIdx.x, w = t>>6, l = t&63, lg = l>>4, l15 = l&15;
    const int wgm = w>>1, wgn = w&1;
    const int r0 = blockIdx.x*64 + wgm*32;
    f32x4 acc[2][12];
    #pragma unroll
    for (int mt=0; mt<2; ++mt)
        #pragma unroll
        for (int nt=0; nt<12; ++nt) acc[mt][nt] = (f32x4){0.f,0.f,0.f,0.f};
    for (int kt=0; kt<12; ++kt) {
        bf16x8 a[2];
        #pragma unroll
        for (int mt=0; mt<2; ++mt) {
            const float* ap = &snx[(size_t)(r0+mt*16+l15)*HIDDEN + kt*32 + lg*8];
            float tmp[8];
            *(float4*)tmp     = *(const float4*)ap;
            *(float4*)(tmp+4) = *(const float4*)(ap+4);
            a[mt] = pack8(tmp);
        }
        const unsigned short* bp = &Wf[((size_t)(kt*24 + wgn*12)*64 + l)*8];
        #pragma unroll
        for (int nt=0; nt<12; ++nt) {
            bf16x8 b = *(const bf16x8*)(bp + (size_t)nt*512);
            acc[0][nt] = __builtin_amdgcn_mfma_f32_16x16x32_bf16(a[0], b, acc[0][nt], 0,0,0);
            acc[1][nt] = __builtin_amdgcn_mfma_f32_16x16x32_bf16(a[1], b, acc[1][nt], 0,0,0);
        }
    }
    #pragma unroll
    for (int mt=0; mt<2; ++mt)
        #pragma unroll
        for (int nt=0; nt<12; ++nt) {
            const int col = wgn*192 + nt*16 + l15;
            #pragma unroll
            for (int r=0; r<4; ++r) {
                const int row = r0 + mt*16 + lg*4 + r;
                dstv[(size_t)row*HIDDEN + col] = acc[mt][nt][r] + b1[col];
            }
        }
}

// ---- the big fused MLP: 512 thr, 8 waves, BM=128 rows (4 supernodes) ----
// wave (mg,ng): mg in {0,1} owns 64 rows, ng in {0..3} owns 96 cols.
__global__ __launch_bounds__(512)
void k_mlp(const float* __restrict__ pos, const float* __restrict__ feat,
           const int* __restrict__ nbr_idx, const void* __restrict__ mask_raw,
           const int* __restrict__ mask_fmt,
           const float* __restrict__ W_in, const float* __restrict__ b_in,
           const float* __restrict__ dstv,
           const unsigned short* __restrict__ W1f,
           const unsigned short* __restrict__ W2f,
           const float* __restrict__ b2, float* __restrict__ agg)
{
    __shared__ unsigned short G[BM][392];      // 100352 B: gelu output (layer-2 A)
    __shared__ unsigned short Akt[2][BM][40];  // 20480 B: embed K-tile, dbuf
    __shared__ float PF[BM][7];                // 3584 B: pos3, feat3, mval
    __shared__ float WINT[HIDDEN][4];          // 6144 B: W_in rows + b_in, transposed
    __shared__ float CNT[4];                   // per-supernode mask count

    const int t  = threadIdx.x;
    const int bm = blockIdx.x;

    if (t < BM) {
        const int e = bm*BM + t;
        const int pi = nbr_idx[e];
        PF[t][0]=pos[pi*3];  PF[t][1]=pos[pi*3+1];  PF[t][2]=pos[pi*3+2];
        PF[t][3]=feat[pi*3]; PF[t][4]=feat[pi*3+1]; PF[t][5]=feat[pi*3+2];
        const int fmt = *mask_fmt;
        const int mv = fmt ? (int)((const unsigned char*)mask_raw)[e]
                           : ((const int*)mask_raw)[e];
        PF[t][6] = mv ? 1.0f : 0.0f;
    }
    if (t >= 128 && t < 128 + HIDDEN) {
        const int d = t - 128;
        WINT[d][0] = W_in[d]; WINT[d][1] = W_in[HIDDEN+d];
        WINT[d][2] = W_in[2*HIDDEN+d]; WINT[d][3] = b_in[d];
    }
    __syncthreads();
    if (t < 4) {
        float c = 0.f;
        for (int s = 0; s < 32; ++s) c += PF[t*32+s][6];
        CNT[t] = c;
    }

    const int w = t>>6, l = t&63, lg = l>>4, l15 = l&15;
    const int mg = w>>2, ng = w&3;
    const int er = t>>2, seg = t&3;    // embed-staging: row, 8-dim segment

    // compute A K-tile kt into Akt[buf] (embeds on the fly; args in [0,1) => __sinf ok)
    auto stage = [&](int kt, int buf) {
        const int cc = kt>>2;
        const int j0 = (kt&3)*32 + seg*8;
        const float pc = PF[er][cc];
        const float f0 = PF[er][3], f1 = PF[er][4], f2 = PF[er][5];
        float v[8];
        #pragma unroll
        for (int i=0; i<8; ++i) {
            const int j = j0 + i;
            const int fi = j & 63;
            const float fr = exp2f(-(float)fi * 0.2076205059304601f);
            const float a = pc * fr;
            const float base = (j < 64) ? __sinf(a) : __cosf(a);
            const float4 wv = *(const float4*)WINT[cc*128 + j];
            v[i] = base + f0*wv.x + f1*wv.y + f2*wv.z + wv.w;
        }
        *(bf16x8*)&Akt[buf][er][seg*8] = pack8(v);
    };

    f32x4 acc[4][6];
    #pragma unroll
    for (int mt=0; mt<4; ++mt)
        #pragma unroll
        for (int nt=0; nt<6; ++nt) acc[mt][nt] = (f32x4){0.f,0.f,0.f,0.f};

    // ---- layer 1: Y = E @ W1src ----
    stage(0, 0);
    __syncthreads();
    for (int kt = 0; kt < 12; ++kt) {
        if (kt < 11) stage(kt+1, (kt+1)&1);
        bf16x8 a[4], b[6];
        const unsigned short* bp = &W1f[((size_t)(kt*24 + ng*6)*64 + l)*8];
        #pragma unroll
        for (int nt=0; nt<6; ++nt) b[nt] = *(const bf16x8*)(bp + (size_t)nt*512);
        #pragma unroll
        for (int mt=0; mt<4; ++mt)
            a[mt] = *(const bf16x8*)&Akt[kt&1][mg*64 + mt*16 + l15][lg*8];
        #pragma unroll
        for (int mt=0; mt<4; ++mt)
            #pragma unroll
            for (int nt=0; nt<6; ++nt)
                acc[mt][nt] = __builtin_amdgcn_mfma_f32_16x16x32_bf16(a[mt], b[nt], acc[mt][nt], 0,0,0);
        __syncthreads();
    }

    // ---- layer-1 epilogue: +dstv, gelu, G (bf16) into LDS ----
    #pragma unroll
    for (int mt=0; mt<4; ++mt) {
        const int sn = bm*4 + mg*2 + (mt>>1);
        #pragma unroll
        for (int nt=0; nt<6; ++nt) {
            const int col = ng*96 + nt*16 + l15;
            const float dv = dstv[(size_t)sn*HIDDEN + col];
            #pragma unroll
            for (int r=0; r<4; ++r) {
                const float y = acc[mt][nt][r] + dv;
                const float g = 0.5f*y*(1.0f + erff(y*0.70710678118654752f));
                G[mg*64 + mt*16 + lg*4 + r][col] = f2bf(g);
            }
        }
    }
    __syncthreads();

    // ---- layer 2: Y2 = G @ W2 (G read from LDS, no staging) ----
    #pragma unroll
    for (int mt=0; mt<4; ++mt)
        #pragma unroll
        for (int nt=0; nt<6; ++nt) acc[mt][nt] = (f32x4){0.f,0.f,0.f,0.f};
    for (int kt = 0; kt < 12; ++kt) {
        bf16x8 a[4], b[6];
        const unsigned short* bp = &W2f[((size_t)(kt*24 + ng*6)*64 + l)*8];
        #pragma unroll
        for (int nt=0; nt<6; ++nt) b[nt] = *(const bf16x8*)(bp + (size_t)nt*512);
        #pragma unroll
        for (int mt=0; mt<4; ++mt)
            a[mt] = *(const bf16x8*)&G[mg*64 + mt*16 + l15][kt*32 + lg*8];
        #pragma unroll
        for (int mt=0; mt<4; ++mt)
            #pragma unroll
            for (int nt=0; nt<6; ++nt)
                acc[mt][nt] = __builtin_amdgcn_mfma_f32_16x16x32_bf16(a[mt], b[nt], acc[mt][nt], 0,0,0);
    }

    // ---- layer-2 epilogue: masked mean -> agg[sn][col] ----
    #pragma unroll
    for (int nt=0; nt<6; ++nt) {
        const int col = ng*96 + nt*16 + l15;
        float s0 = 0.f, s1 = 0.f;
        #pragma unroll
        for (int mt=0; mt<4; ++mt) {
            float p = 0.f;
            #pragma unroll
            for (int r=0; r<4; ++r) {
                const int row = mg*64 + mt*16 + lg*4 + r;
                p += PF[row][6] * acc[mt][nt][r];
            }
            if (mt < 2) s0 += p; else s1 += p;
        }
        s0 += __shfl_xor(s0,16); s0 += __shfl_xor(s0,32);
        s1 += __shfl_xor(s1,16); s1 += __shfl_xor(s1,32);
        if (lg == 0) {
            const float bb = b2[col];
            const int sn0 = bm*4 + mg*2;
            const float c0 = CNT[mg*2], c1 = CNT[mg*2+1];
            agg[(size_t)sn0*HIDDEN + col]     = s0 / fmaxf(c0,1.f) + bb*(c0>0.f?1.f:0.f);
            agg[(size_t)(sn0+1)*HIDDEN + col] = s1 / fmaxf(c1,1.f) + bb*(c1>0.f?1.f:0.f);
        }
    }
}

// ---- projection: out[2048][384] = bf16([agg|snx]) @ Wp + bp ----
__global__ __launch_bounds__(256)
void k_proj(const float* __restrict__ agg, const float* __restrict__ snx,
            const unsigned short* __restrict__ Wpf,
            const float* __restrict__ bp, float* __restrict__ out) {
    const int t = threadIdx.x, w = t>>6, l = t&63, lg = l>>4, l15 = l&15;
    const int wgm = w>>1, wgn = w&1;
    const int r0 = blockIdx.x*64 + wgm*32;
    f32x4 acc[2][12];
    #pragma unroll
    for (int mt=0; mt<2; ++mt)
        #pragma unroll
        for (int nt=0; nt<12; ++nt) acc[mt][nt] = (f32x4){0.f,0.f,0.f,0.f};
    for (int kt=0; kt<24; ++kt) {
        const float* Ab = (kt < 12) ? agg : snx;
        const int kk = (kt < 12) ? kt*32 : (kt-12)*32;
        bf16x8 a[2];
        #pragma unroll
        for (int mt=0; mt<2; ++mt) {
            const float* ap = &Ab[(size_t)(r0+mt*16+l15)*HIDDEN + kk + lg*8];
            float tmp[8];
            *(float4*)tmp     = *(const float4*)ap;
            *(float4*)(tmp+4) = *(const float4*)(ap+4);
            a[mt] = pack8(tmp);
        }
        const unsigned short* bpp = &Wpf[((size_t)(kt*24 + wgn*12)*64 + l)*8];
        #pragma unroll
        for (int nt=0; nt<12; ++nt) {
            bf16x8 b = *(const bf16x8*)(bpp + (size_t)nt*512);
            acc[0][nt] = __builtin_amdgcn_mfma_f32_16x16x32_bf16(a[0], b, acc[0][nt], 0,0,0);
            acc[1][nt] = __builtin_amdgcn_mfma_f32_16x16x32_bf16(a[1], b, acc[1][nt], 0,0,0);
        }
    }
    #pragma unroll
    for (int mt=0; mt<2; ++mt)
        #pragma unroll
        for (int nt=0; nt<12; ++nt) {
            const int col = wgn*192 + nt*16 + l15;
            #pragma unroll
            for (int r=0; r<4; ++r) {
                const int row = r0 + mt*16 + lg*4 + r;
                out[(size_t)row*HIDDEN + col] = acc[mt][nt][r] + bp[col];
            }
        }
}

extern "C" void kernel_launch(void* const* d_in, const int* in_sizes, int n_in,
                              void* d_out, int out_size, void* d_ws, size_t ws_size,
                              hipStream_t stream) {
    const float* pos   = (const float*)d_in[0];
    const float* feat  = (const float*)d_in[1];
    const int*   sn    = (const int*)d_in[2];
    const int*   nbr   = (const int*)d_in[3];
    const void*  mask  = d_in[4];
    const float* W_in  = (const float*)d_in[5];
    const float* b_in  = (const float*)d_in[6];
    const float* W1    = (const float*)d_in[7];
    const float* b1    = (const float*)d_in[8];
    const float* W2    = (const float*)d_in[9];
    const float* b2    = (const float*)d_in[10];
    const float* Wp    = (const float*)d_in[11];
    const float* bpv   = (const float*)d_in[12];
    float* out = (float*)d_out;

    char* base = (char*)d_ws;
    int* flag = (int*)base;
    unsigned short* w1sf = (unsigned short*)(base + 256);
    unsigned short* w1df = w1sf + 147456;
    unsigned short* w2f  = w1df + 147456;
    unsigned short* wpf  = w2f  + 147456;          // 2x147456 shorts (768 rows)
    float* snx  = (float*)(base + 256 + 294912*5); // 2048*384 f32
    float* dstv = snx  + (size_t)NSUPER*HIDDEN;
    float* agg  = dstv + (size_t)NSUPER*HIDDEN;
    // total ws use ~10.9 MB

    hipLaunchKernelGGL(detect_mask_fmt, dim3(1), dim3(256), 0, stream,
                       (const unsigned int*)mask, flag);
    hipLaunchKernelGGL(repack_w, dim3(72), dim3(256), 0, stream, W1, w1sf);
    hipLaunchKernelGGL(repack_w, dim3(72), dim3(256), 0, stream, W1 + 384*HIDDEN, w1df);
    hipLaunchKernelGGL(repack_w, dim3(72), dim3(256), 0, stream, W2, w2f);
    hipLaunchKernelGGL(repack_w, dim3(72), dim3(256), 0, stream, Wp, wpf);
    hipLaunchKernelGGL(repack_w, dim3(72), dim3(256), 0, stream, Wp + 384*HIDDEN, wpf + 147456);
    hipLaunchKernelGGL(k_snx,  dim3(NSUPER), dim3(128), 0, stream,
                       pos, feat, sn, W_in, b_in, snx);
    hipLaunchKernelGGL(k_dstv, dim3(32), dim3(256), 0, stream, snx, w1df, b1, dstv);
    hipLaunchKernelGGL(k_mlp,  dim3(512), dim3(512), 0, stream,
                       pos, feat, nbr, mask, flag, W_in, b_in, dstv, w1sf, w2f, b2, agg);
    hipLaunchKernelGGL(k_proj, dim3(32), dim3(256), 0, stream, agg, snx, wpf, bpv, out);
}

// Round 5
// 102.349 us; speedup vs baseline: 48.0528x; 1.6771x over previous
//
#include <hip/hip_runtime.h>
#include <hip/hip_bf16.h>
#include <cstdint>

#define HIDDEN 384
#define NSUPER 2048
#define MAXDEG 32
#define BM 128
#define FRAGS (12*24*64)            // fragments*lanes per 384x384 block
#define WBLK  (FRAGS*8)             // shorts per repacked 384x384 block = 147456

typedef __attribute__((ext_vector_type(8))) short bf16x8;
typedef __attribute__((ext_vector_type(4))) float f32x4;

#define SWZ(row, col) ((col) ^ (((row)&7)<<3))   // T2 XOR swizzle on short index

__device__ inline unsigned short f2bf(float f) {
    __hip_bfloat16 h = __float2bfloat16(f);   // RNE
    return *reinterpret_cast<unsigned short*>(&h);
}
__device__ inline bf16x8 pack8(const float* v) {
    union { bf16x8 v8; unsigned short u[8]; } u;
    #pragma unroll
    for (int i = 0; i < 8; ++i) u.u[i] = f2bf(v[i]);
    return u.v8;
}
// Abramowitz-Stegun 7.1.26: |err| <= 1.5e-7, branchless (~14 VALU ops)
__device__ inline float fast_erf(float x) {
    float ax = fabsf(x);
    float t  = 1.0f / fmaf(0.3275911f, ax, 1.0f);
    float p  = t*(0.254829592f + t*(-0.284496736f + t*(1.421413741f +
               t*(-1.453152027f + t*1.061405429f))));
    float e  = __expf(-ax*ax);
    return copysignf(1.0f - p*e, x);
}
__device__ inline float gelu(float y) {
    return 0.5f * y * (1.0f + fast_erf(y * 0.70710678118654752f));
}

// ---- prep: 5 weight repacks + mask-format detect, one launch ----
// frag (kt,nt): lane l elem j = W[kt*32 + (l>>4)*8 + j][nt*16 + (l&15)]
__global__ __launch_bounds__(256)
void prep(const float* __restrict__ W1, const float* __restrict__ W2,
          const float* __restrict__ Wp, const unsigned int* __restrict__ mask,
          unsigned short* __restrict__ w1sf, unsigned short* __restrict__ w1df,
          unsigned short* __restrict__ w2f,  unsigned short* __restrict__ wpf,
          int* __restrict__ flag) {
    const int b = blockIdx.x;
    if (b == 360) {   // mask detect: uint8 numpy-bool vs int32
        __shared__ int s;
        if (threadIdx.x == 0) s = 0;
        __syncthreads();
        int bad = 0;
        for (int i = threadIdx.x; i < 16384; i += 256)
            if (mask[i] > 1u) bad = 1;
        if (bad) s = 1;
        __syncthreads();
        if (threadIdx.x == 0) *flag = s;   // 1 => uint8, 0 => int32
        return;
    }
    const int grp = b / 72, sub = b % 72;
    const float* W; unsigned short* out;
    switch (grp) {
        case 0: W = W1;              out = w1sf; break;
        case 1: W = W1 + 384*HIDDEN; out = w1df; break;
        case 2: W = W2;              out = w2f;  break;
        case 3: W = Wp;              out = wpf;  break;
        default:W = Wp + 384*HIDDEN; out = wpf + WBLK; break;
    }
    const int idx = sub * 256 + threadIdx.x;   // 72*256 == FRAGS exactly
    const int l   = idx & 63;
    const int frag= idx >> 6;
    const int nt  = frag % 24;
    const int kt  = frag / 24;
    const int col = nt * 16 + (l & 15);
    const int k0  = kt * 32 + (l >> 4) * 8;
    unsigned int pk[4];
    #pragma unroll
    for (int j = 0; j < 4; ++j) {
        unsigned int lo = f2bf(W[(k0 + 2*j)     * HIDDEN + col]);
        unsigned int hi = f2bf(W[(k0 + 2*j + 1) * HIDDEN + col]);
        pk[j] = lo | (hi << 16);
    }
    *reinterpret_cast<uint4*>(&out[(size_t)idx * 8]) =
        *reinterpret_cast<const uint4*>(pk);
}

// ---- fused supernode embed + dstv GEMM ----
// grid 64 = 32 row-groups x 2 col-halves. 256 thr (4 waves: 2 wgm x 2 wgn).
__global__ __launch_bounds__(256)
void k_embdst(const float* __restrict__ pos, const float* __restrict__ feat,
              const int* __restrict__ sn_idx,
              const float* __restrict__ W_in, const float* __restrict__ b_in,
              const unsigned short* __restrict__ W1df, const float* __restrict__ b1,
              unsigned short* __restrict__ snxb, float* __restrict__ dstv)
{
    __shared__ unsigned short E[64][384];   // swizzled bf16 supernode embeds
    __shared__ float WINT[HIDDEN][4];
    __shared__ float PF[64][8];
    __shared__ float FREQ[64];

    const int rg = blockIdx.x >> 1, ch = blockIdx.x & 1;
    const int t  = threadIdx.x;

    if (t < 64) {
        const int pi = sn_idx[rg*64 + t];
        PF[t][0]=pos[pi*3];  PF[t][1]=pos[pi*3+1];  PF[t][2]=pos[pi*3+2];
        PF[t][3]=feat[pi*3]; PF[t][4]=feat[pi*3+1]; PF[t][5]=feat[pi*3+2];
        FREQ[t] = exp2f(-(float)t * 0.2076205059304601f);  // 10000^(-t/64)
    }
    for (int d = t; d < HIDDEN; d += 256) {
        WINT[d][0]=W_in[d]; WINT[d][1]=W_in[HIDDEN+d];
        WINT[d][2]=W_in[2*HIDDEN+d]; WINT[d][3]=b_in[d];
    }
    __syncthreads();

    // embed 64 rows x 384 dims
    const int er = t >> 2, seg = t & 3;
    #pragma unroll
    for (int blk = 0; blk < 12; ++blk) {
        const int dim0 = blk*32 + seg*8;
        float v[8];
        #pragma unroll
        for (int i = 0; i < 8; ++i) {
            const int dim = dim0 + i;
            const int cc  = dim >> 7;
            const float a = PF[er][cc] * FREQ[dim & 63];
            const float base = ((dim >> 6) & 1) ? __cosf(a) : __sinf(a);
            const float4 wv = *(const float4*)WINT[dim];
            v[i] = base + PF[er][3]*wv.x + PF[er][4]*wv.y + PF[er][5]*wv.z + wv.w;
        }
        const bf16x8 pk = pack8(v);
        *(bf16x8*)&E[er][SWZ(er, dim0)] = pk;
        if (ch == 0)
            *(bf16x8*)&snxb[(size_t)(rg*64 + er)*HIDDEN + dim0] = pk;
    }
    __syncthreads();

    // dstv GEMM: rows 64 (this rg), cols 192 (this ch)
    const int w = t>>6, l = t&63, lg = l>>4, l15 = l&15;
    const int wgm = w>>1, wgn = w&1;
    f32x4 acc[2][6];
    #pragma unroll
    for (int mt=0; mt<2; ++mt)
        #pragma unroll
        for (int nt=0; nt<6; ++nt) acc[mt][nt] = (f32x4){0.f,0.f,0.f,0.f};
    const int ntb = (ch*2 + wgn) * 6;
    for (int kt = 0; kt < 12; ++kt) {
        bf16x8 a[2], bfr[6];
        const unsigned short* bp = &W1df[((size_t)(kt*24 + ntb)*64 + l)*8];
        #pragma unroll
        for (int nt=0; nt<6; ++nt) bfr[nt] = *(const bf16x8*)(bp + (size_t)nt*512);
        #pragma unroll
        for (int mt=0; mt<2; ++mt)
            a[mt] = *(const bf16x8*)&E[wgm*32 + mt*16 + l15][SWZ(l15, kt*32 + lg*8)];
        #pragma unroll
        for (int mt=0; mt<2; ++mt)
            #pragma unroll
            for (int nt=0; nt<6; ++nt)
                acc[mt][nt] = __builtin_amdgcn_mfma_f32_16x16x32_bf16(a[mt], bfr[nt], acc[mt][nt], 0,0,0);
    }
    #pragma unroll
    for (int mt=0; mt<2; ++mt)
        #pragma unroll
        for (int nt=0; nt<6; ++nt) {
            const int col = ch*192 + wgn*96 + nt*16 + l15;
            #pragma unroll
            for (int r=0; r<4; ++r) {
                const int row = rg*64 + wgm*32 + mt*16 + lg*4 + r;
                dstv[(size_t)row*HIDDEN + col] = acc[mt][nt][r] + b1[col];
            }
        }
}

// ---- fused edge MLP: 512 thr (8 waves: 2 mg x 4 ng), BM=128 rows ----
__global__ __launch_bounds__(512)
void k_mlp(const float* __restrict__ pos, const float* __restrict__ feat,
           const int* __restrict__ nbr_idx, const void* __restrict__ mask_raw,
           const int* __restrict__ mask_fmt,
           const float* __restrict__ W_in, const float* __restrict__ b_in,
           const float* __restrict__ dstv,
           const unsigned short* __restrict__ W1f,
           const unsigned short* __restrict__ W2f,
           const float* __restrict__ b2, unsigned short* __restrict__ aggb)
{
    __shared__ unsigned short G[BM][384];   // swizzled bf16: embeds, then gelu out
    __shared__ float WINT[HIDDEN][4];
    __shared__ float DSTV[4][HIDDEN];
    __shared__ float PF[BM][8];
    __shared__ float FREQ[64];
    __shared__ float CNT[4];

    const int t  = threadIdx.x;
    const int bm = blockIdx.x;

    if (t < BM) {
        const int e  = bm*BM + t;
        const int pi = nbr_idx[e];
        PF[t][0]=pos[pi*3];  PF[t][1]=pos[pi*3+1];  PF[t][2]=pos[pi*3+2];
        PF[t][3]=feat[pi*3]; PF[t][4]=feat[pi*3+1]; PF[t][5]=feat[pi*3+2];
        const int fmt = *mask_fmt;
        const int mv  = fmt ? (int)((const unsigned char*)mask_raw)[e]
                            : ((const int*)mask_raw)[e];
        PF[t][6] = mv ? 1.0f : 0.0f;
    }
    if (t >= 128) {   // 384 threads cover WINT
        const int d = t - 128;
        WINT[d][0]=W_in[d]; WINT[d][1]=W_in[HIDDEN+d];
        WINT[d][2]=W_in[2*HIDDEN+d]; WINT[d][3]=b_in[d];
    }
    if (t < 64) FREQ[t] = exp2f(-(float)t * 0.2076205059304601f);
    for (int i = t; i < 4*HIDDEN; i += 512)
        ((float*)DSTV)[i] = dstv[(size_t)bm*4*HIDDEN + i];
    __syncthreads();
    if (t < 4) {
        float c = 0.f;
        for (int s = 0; s < 32; ++s) c += PF[t*32+s][6];
        CNT[t] = c;   // visible after next barrier
    }

    // ---- embed all 128 rows x 384 dims into G ----
    {
        const int er = t >> 2, seg = t & 3;
        #pragma unroll
        for (int blk = 0; blk < 12; ++blk) {
            const int dim0 = blk*32 + seg*8;
            float v[8];
            #pragma unroll
            for (int i = 0; i < 8; ++i) {
                const int dim = dim0 + i;
                const int cc  = dim >> 7;
                const float a = PF[er][cc] * FREQ[dim & 63];
                const float base = ((dim >> 6) & 1) ? __cosf(a) : __sinf(a);
                const float4 wv = *(const float4*)WINT[dim];
                v[i] = base + PF[er][3]*wv.x + PF[er][4]*wv.y + PF[er][5]*wv.z + wv.w;
            }
            *(bf16x8*)&G[er][SWZ(er, dim0)] = pack8(v);
        }
    }
    __syncthreads();

    const int w = t>>6, l = t&63, lg = l>>4, l15 = l&15;
    const int mg = w>>2, ng = w&3;

    f32x4 acc[4][6];
    #pragma unroll
    for (int mt=0; mt<4; ++mt)
        #pragma unroll
        for (int nt=0; nt<6; ++nt) acc[mt][nt] = (f32x4){0.f,0.f,0.f,0.f};

    // ---- layer 1: no internal barriers ----
    #pragma unroll 2
    for (int kt = 0; kt < 12; ++kt) {
        bf16x8 a[4], bfr[6];
        const unsigned short* bp = &W1f[((size_t)(kt*24 + ng*6)*64 + l)*8];
        #pragma unroll
        for (int nt=0; nt<6; ++nt) bfr[nt] = *(const bf16x8*)(bp + (size_t)nt*512);
        #pragma unroll
        for (int mt=0; mt<4; ++mt)
            a[mt] = *(const bf16x8*)&G[mg*64 + mt*16 + l15][SWZ(l15, kt*32 + lg*8)];
        #pragma unroll
        for (int mt=0; mt<4; ++mt)
            #pragma unroll
            for (int nt=0; nt<6; ++nt)
                acc[mt][nt] = __builtin_amdgcn_mfma_f32_16x16x32_bf16(a[mt], bfr[nt], acc[mt][nt], 0,0,0);
    }
    __syncthreads();   // all E reads done

    // ---- gelu epilogue -> G ----
    #pragma unroll
    for (int mt=0; mt<4; ++mt) {
        const int sl = mg*2 + (mt>>1);   // supernode slot in block
        #pragma unroll
        for (int nt=0; nt<6; ++nt) {
            const int col = ng*96 + nt*16 + l15;
            const float dv = DSTV[sl][col];
            #pragma unroll
            for (int r=0; r<4; ++r) {
                const int row = mg*64 + mt*16 + lg*4 + r;
                G[row][SWZ(row, col)] = f2bf(gelu(acc[mt][nt][r] + dv));
            }
        }
    }
    __syncthreads();

    // ---- layer 2 ----
    #pragma unroll
    for (int mt=0; mt<4; ++mt)
        #pragma unroll
        for (int nt=0; nt<6; ++nt) acc[mt][nt] = (f32x4){0.f,0.f,0.f,0.f};
    #pragma unroll 2
    for (int kt = 0; kt < 12; ++kt) {
        bf16x8 a[4], bfr[6];
        const unsigned short* bp = &W2f[((size_t)(kt*24 + ng*6)*64 + l)*8];
        #pragma unroll
        for (int nt=0; nt<6; ++nt) bfr[nt] = *(const bf16x8*)(bp + (size_t)nt*512);
        #pragma unroll
        for (int mt=0; mt<4; ++mt)
            a[mt] = *(const bf16x8*)&G[mg*64 + mt*16 + l15][SWZ(l15, kt*32 + lg*8)];
        #pragma unroll
        for (int mt=0; mt<4; ++mt)
            #pragma unroll
            for (int nt=0; nt<6; ++nt)
                acc[mt][nt] = __builtin_amdgcn_mfma_f32_16x16x32_bf16(a[mt], bfr[nt], acc[mt][nt], 0,0,0);
    }

    // ---- masked mean -> aggb (bf16, b2 added) ----
    #pragma unroll
    for (int nt=0; nt<6; ++nt) {
        const int col = ng*96 + nt*16 + l15;
        float s0 = 0.f, s1 = 0.f;
        #pragma unroll
        for (int mt=0; mt<4; ++mt) {
            float p = 0.f;
            #pragma unroll
            for (int r=0; r<4; ++r)
                p += PF[mg*64 + mt*16 + lg*4 + r][6] * acc[mt][nt][r];
            if (mt < 2) s0 += p; else s1 += p;
        }
        s0 += __shfl_xor(s0,16); s0 += __shfl_xor(s0,32);
        s1 += __shfl_xor(s1,16); s1 += __shfl_xor(s1,32);
        if (lg == 0) {
            const float bb = b2[col];
            const int sn0 = bm*4 + mg*2;
            const float c0 = CNT[mg*2], c1 = CNT[mg*2+1];
            aggb[(size_t)sn0*HIDDEN + col]     = f2bf(s0 / fmaxf(c0,1.f) + bb*(c0>0.f?1.f:0.f));
            aggb[(size_t)(sn0+1)*HIDDEN + col] = f2bf(s1 / fmaxf(c1,1.f) + bb*(c1>0.f?1.f:0.f));
        }
    }
}

// ---- projection: out = [aggb|snxb] @ Wp + bp.  128 blocks = 32 rg x 4 cq ----
__global__ __launch_bounds__(256)
void k_proj(const unsigned short* __restrict__ aggb,
            const unsigned short* __restrict__ snxb,
            const unsigned short* __restrict__ wpf,
            const float* __restrict__ bp, float* __restrict__ out) {
    const int rg = blockIdx.x >> 2, cq = blockIdx.x & 3;
    const int t = threadIdx.x, w = t>>6, l = t&63, lg = l>>4, l15 = l&15;
    const int wgm = w>>1, wgn = w&1;
    const int r0 = rg*64 + wgm*32;
    const int ntb = cq*6 + wgn*3;
    f32x4 acc[2][3];
    #pragma unroll
    for (int mt=0; mt<2; ++mt)
        #pragma unroll
        for (int nt=0; nt<3; ++nt) acc[mt][nt] = (f32x4){0.f,0.f,0.f,0.f};
    #pragma unroll 2
    for (int kt = 0; kt < 24; ++kt) {
        const unsigned short* Ab = (kt < 12) ? aggb : snxb;
        const unsigned short* Wb = (kt < 12) ? wpf  : wpf + WBLK;
        const int ktt = (kt < 12) ? kt : kt - 12;
        bf16x8 a[2], bfr[3];
        const unsigned short* bpp = &Wb[((size_t)(ktt*24 + ntb)*64 + l)*8];
        #pragma unroll
        for (int nt=0; nt<3; ++nt) bfr[nt] = *(const bf16x8*)(bpp + (size_t)nt*512);
        #pragma unroll
        for (int mt=0; mt<2; ++mt)
            a[mt] = *(const bf16x8*)&Ab[(size_t)(r0 + mt*16 + l15)*HIDDEN + ktt*32 + lg*8];
        #pragma unroll
        for (int mt=0; mt<2; ++mt)
            #pragma unroll
            for (int nt=0; nt<3; ++nt)
                acc[mt][nt] = __builtin_amdgcn_mfma_f32_16x16x32_bf16(a[mt], bfr[nt], acc[mt][nt], 0,0,0);
    }
    #pragma unroll
    for (int mt=0; mt<2; ++mt)
        #pragma unroll
        for (int nt=0; nt<3; ++nt) {
            const int col = cq*96 + wgn*48 + nt*16 + l15;
            #pragma unroll
            for (int r=0; r<4; ++r) {
                const int row = r0 + mt*16 + lg*4 + r;
                out[(size_t)row*HIDDEN + col] = acc[mt][nt][r] + bp[col];
            }
        }
}

extern "C" void kernel_launch(void* const* d_in, const int* in_sizes, int n_in,
                              void* d_out, int out_size, void* d_ws, size_t ws_size,
                              hipStream_t stream) {
    const float* pos   = (const float*)d_in[0];
    const float* feat  = (const float*)d_in[1];
    const int*   sn    = (const int*)d_in[2];
    const int*   nbr   = (const int*)d_in[3];
    const void*  mask  = d_in[4];
    const float* W_in  = (const float*)d_in[5];
    const float* b_in  = (const float*)d_in[6];
    const float* W1    = (const float*)d_in[7];
    const float* b1    = (const float*)d_in[8];
    const float* W2    = (const float*)d_in[9];
    const float* b2    = (const float*)d_in[10];
    const float* Wp    = (const float*)d_in[11];
    const float* bpv   = (const float*)d_in[12];
    float* out = (float*)d_out;

    char* base = (char*)d_ws;
    int* flag = (int*)base;
    unsigned short* w1sf = (unsigned short*)(base + 256);
    unsigned short* w1df = w1sf + WBLK;
    unsigned short* w2f  = w1df + WBLK;
    unsigned short* wpf  = w2f  + WBLK;                  // 2 blocks (768 rows)
    unsigned short* snxb = wpf  + 2*(size_t)WBLK;        // 2048*384 bf16
    unsigned short* aggb = snxb + (size_t)NSUPER*HIDDEN;
    float* dstv = (float*)(aggb + (size_t)NSUPER*HIDDEN); // 2048*384 f32
    // total ws use ~7.8 MB

    hipLaunchKernelGGL(prep, dim3(361), dim3(256), 0, stream,
                       W1, W2, Wp, (const unsigned int*)mask, w1sf, w1df, w2f, wpf, flag);
    hipLaunchKernelGGL(k_embdst, dim3(64), dim3(256), 0, stream,
                       pos, feat, sn, W_in, b_in, w1df, b1, snxb, dstv);
    hipLaunchKernelGGL(k_mlp, dim3(512), dim3(512), 0, stream,
                       pos, feat, nbr, mask, flag, W_in, b_in, dstv, w1sf, w2f, b2, aggb);
    hipLaunchKernelGGL(k_proj, dim3(128), dim3(256), 0, stream,
                       aggb, snxb, wpf, bpv, out);
}

// Round 6
// 94.985 us; speedup vs baseline: 51.7783x; 1.0775x over previous
//
#include <hip/hip_runtime.h>
#include <hip/hip_bf16.h>
#include <cstdint>

#define HIDDEN 384
#define NSUPER 2048
#define MAXDEG 32
#define FRAGS (12*24*64)            // fragments*lanes per 384x384 block
#define WBLK  (FRAGS*8)             // shorts per repacked 384x384 block = 147456

typedef __attribute__((ext_vector_type(8))) short bf16x8;
typedef __attribute__((ext_vector_type(4))) float f32x4;

#define SWZ(row, col) ((col) ^ (((row)&7)<<3))   // used only in k_embdst (tiny kernel)

__device__ inline unsigned short f2bf(float f) {
    __hip_bfloat16 h = __float2bfloat16(f);   // RNE
    return *reinterpret_cast<unsigned short*>(&h);
}
__device__ inline bf16x8 pack8(const float* v) {
    union { bf16x8 v8; unsigned short u[8]; } u;
    #pragma unroll
    for (int i = 0; i < 8; ++i) u.u[i] = f2bf(v[i]);
    return u.v8;
}
// Abramowitz-Stegun 7.1.26: |err| <= 1.5e-7, branchless
__device__ inline float fast_erf(float x) {
    float ax = fabsf(x);
    float t  = 1.0f / fmaf(0.3275911f, ax, 1.0f);
    float p  = t*(0.254829592f + t*(-0.284496736f + t*(1.421413741f +
               t*(-1.453152027f + t*1.061405429f))));
    float e  = __expf(-ax*ax);
    return copysignf(1.0f - p*e, x);
}
__device__ inline float gelu(float y) {
    return 0.5f * y * (1.0f + fast_erf(y * 0.70710678118654752f));
}

// ---- prep: 5 weight repacks + mask-format detect, one launch ----
// frag (kt,nt): lane l elem j = W[kt*32 + (l>>4)*8 + j][nt*16 + (l&15)]
__global__ __launch_bounds__(256)
void prep(const float* __restrict__ W1, const float* __restrict__ W2,
          const float* __restrict__ Wp, const unsigned int* __restrict__ mask,
          unsigned short* __restrict__ w1sf, unsigned short* __restrict__ w1df,
          unsigned short* __restrict__ w2f,  unsigned short* __restrict__ wpf,
          int* __restrict__ flag) {
    const int b = blockIdx.x;
    if (b == 360) {   // mask detect: uint8 numpy-bool vs int32
        __shared__ int s;
        if (threadIdx.x == 0) s = 0;
        __syncthreads();
        int bad = 0;
        for (int i = threadIdx.x; i < 16384; i += 256)
            if (mask[i] > 1u) bad = 1;
        if (bad) s = 1;
        __syncthreads();
        if (threadIdx.x == 0) *flag = s;   // 1 => uint8, 0 => int32
        return;
    }
    const int grp = b / 72, sub = b % 72;
    const float* W; unsigned short* out;
    switch (grp) {
        case 0: W = W1;              out = w1sf; break;
        case 1: W = W1 + 384*HIDDEN; out = w1df; break;
        case 2: W = W2;              out = w2f;  break;
        case 3: W = Wp;              out = wpf;  break;
        default:W = Wp + 384*HIDDEN; out = wpf + WBLK; break;
    }
    const int idx = sub * 256 + threadIdx.x;   // 72*256 == FRAGS exactly
    const int l   = idx & 63;
    const int frag= idx >> 6;
    const int nt  = frag % 24;
    const int kt  = frag / 24;
    const int col = nt * 16 + (l & 15);
    const int k0  = kt * 32 + (l >> 4) * 8;
    unsigned int pk[4];
    #pragma unroll
    for (int j = 0; j < 4; ++j) {
        unsigned int lo = f2bf(W[(k0 + 2*j)     * HIDDEN + col]);
        unsigned int hi = f2bf(W[(k0 + 2*j + 1) * HIDDEN + col]);
        pk[j] = lo | (hi << 16);
    }
    *reinterpret_cast<uint4*>(&out[(size_t)idx * 8]) =
        *reinterpret_cast<const uint4*>(pk);
}

// ---- fused supernode embed + dstv GEMM (unchanged from r5) ----
__global__ __launch_bounds__(256)
void k_embdst(const float* __restrict__ pos, const float* __restrict__ feat,
              const int* __restrict__ sn_idx,
              const float* __restrict__ W_in, const float* __restrict__ b_in,
              const unsigned short* __restrict__ W1df, const float* __restrict__ b1,
              unsigned short* __restrict__ snxb, float* __restrict__ dstv)
{
    __shared__ unsigned short E[64][384];
    __shared__ float WINT[HIDDEN][4];
    __shared__ float PF[64][8];
    __shared__ float FREQ[64];

    const int rg = blockIdx.x >> 1, ch = blockIdx.x & 1;
    const int t  = threadIdx.x;

    if (t < 64) {
        const int pi = sn_idx[rg*64 + t];
        PF[t][0]=pos[pi*3];  PF[t][1]=pos[pi*3+1];  PF[t][2]=pos[pi*3+2];
        PF[t][3]=feat[pi*3]; PF[t][4]=feat[pi*3+1]; PF[t][5]=feat[pi*3+2];
        FREQ[t] = exp2f(-(float)t * 0.2076205059304601f);  // 10000^(-t/64)
    }
    for (int d = t; d < HIDDEN; d += 256) {
        WINT[d][0]=W_in[d]; WINT[d][1]=W_in[HIDDEN+d];
        WINT[d][2]=W_in[2*HIDDEN+d]; WINT[d][3]=b_in[d];
    }
    __syncthreads();

    const int er = t >> 2, seg = t & 3;
    #pragma unroll
    for (int blk = 0; blk < 12; ++blk) {
        const int dim0 = blk*32 + seg*8;
        float v[8];
        #pragma unroll
        for (int i = 0; i < 8; ++i) {
            const int dim = dim0 + i;
            const int cc  = dim >> 7;
            const float a = PF[er][cc] * FREQ[dim & 63];
            const float base = ((dim >> 6) & 1) ? __cosf(a) : __sinf(a);
            const float4 wv = *(const float4*)WINT[dim];
            v[i] = base + PF[er][3]*wv.x + PF[er][4]*wv.y + PF[er][5]*wv.z + wv.w;
        }
        const bf16x8 pk = pack8(v);
        *(bf16x8*)&E[er][SWZ(er, dim0)] = pk;
        if (ch == 0)
            *(bf16x8*)&snxb[(size_t)(rg*64 + er)*HIDDEN + dim0] = pk;
    }
    __syncthreads();

    const int w = t>>6, l = t&63, lg = l>>4, l15 = l&15;
    const int wgm = w>>1, wgn = w&1;
    f32x4 acc[2][6];
    #pragma unroll
    for (int mt=0; mt<2; ++mt)
        #pragma unroll
        for (int nt=0; nt<6; ++nt) acc[mt][nt] = (f32x4){0.f,0.f,0.f,0.f};
    const int ntb = (ch*2 + wgn) * 6;
    for (int kt = 0; kt < 12; ++kt) {
        bf16x8 a[2], bfr[6];
        const unsigned short* bp = &W1df[((size_t)(kt*24 + ntb)*64 + l)*8];
        #pragma unroll
        for (int nt=0; nt<6; ++nt) bfr[nt] = *(const bf16x8*)(bp + (size_t)nt*512);
        #pragma unroll
        for (int mt=0; mt<2; ++mt)
            a[mt] = *(const bf16x8*)&E[wgm*32 + mt*16 + l15][SWZ(l15, kt*32 + lg*8)];
        #pragma unroll
        for (int mt=0; mt<2; ++mt)
            #pragma unroll
            for (int nt=0; nt<6; ++nt)
                acc[mt][nt] = __builtin_amdgcn_mfma_f32_16x16x32_bf16(a[mt], bfr[nt], acc[mt][nt], 0,0,0);
    }
    #pragma unroll
    for (int mt=0; mt<2; ++mt)
        #pragma unroll
        for (int nt=0; nt<6; ++nt) {
            const int col = ch*192 + wgn*96 + nt*16 + l15;
            #pragma unroll
            for (int r=0; r<4; ++r) {
                const int row = rg*64 + wgm*32 + mt*16 + lg*4 + r;
                dstv[(size_t)row*HIDDEN + col] = acc[mt][nt][r] + b1[col];
            }
        }
}

// ---- fused edge MLP: 256 thr (4 waves, each owns all 64 rows x 96 cols) ----
// BM=64 rows = 2 supernodes/block; grid 1024. LDS ~61 KB -> 2 blocks/CU.
// G is FRAGMENT-MAJOR: slot(mtile,kt,lane) at shorts ((mtile*12+kt)*64+lane)*8;
// lane l of an MFMA A-read gets row=(l&15), k=kt*32+(l>>4)*8.. -> contiguous
// 1024B per wave read (conflict-free), linear writes from the embed stage.
__global__ __launch_bounds__(256, 2)
void k_mlp(const float* __restrict__ pos, const float* __restrict__ feat,
           const int* __restrict__ nbr_idx, const void* __restrict__ mask_raw,
           const int* __restrict__ mask_fmt,
           const float* __restrict__ W_in, const float* __restrict__ b_in,
           const float* __restrict__ dstv,
           const unsigned short* __restrict__ W1f,
           const unsigned short* __restrict__ W2f,
           const float* __restrict__ b2, unsigned short* __restrict__ aggb)
{
    __shared__ unsigned short G[4*12*64*8];   // 49152 B frag-major
    __shared__ float WINT[HIDDEN][4];
    __shared__ float DSTV[2][HIDDEN];
    __shared__ float PF[64][8];
    __shared__ float CNT[2];

    const int t  = threadIdx.x;
    const int bm = blockIdx.x;

    if (t < 64) {
        const int e  = bm*64 + t;
        const int pi = nbr_idx[e];
        PF[t][0]=pos[pi*3];  PF[t][1]=pos[pi*3+1];  PF[t][2]=pos[pi*3+2];
        PF[t][3]=feat[pi*3]; PF[t][4]=feat[pi*3+1]; PF[t][5]=feat[pi*3+2];
        const int fmt = *mask_fmt;
        const int mv  = fmt ? (int)((const unsigned char*)mask_raw)[e]
                            : ((const int*)mask_raw)[e];
        PF[t][6] = mv ? 1.0f : 0.0f;
    }
    for (int d = t; d < HIDDEN; d += 256) {
        WINT[d][0]=W_in[d]; WINT[d][1]=W_in[HIDDEN+d];
        WINT[d][2]=W_in[2*HIDDEN+d]; WINT[d][3]=b_in[d];
    }
    for (int i = t; i < 2*HIDDEN; i += 256)
        ((float*)DSTV)[i] = dstv[(size_t)bm*2*HIDDEN + i];
    __syncthreads();
    if (t < 2) {
        float c = 0.f;
        for (int s = 0; s < 32; ++s) c += PF[t*32+s][6];
        CNT[t] = c;   // read after later barriers
    }

    // ---- embed 64 rows x 384 dims straight into frag-major G ----
    {
        const int er = t >> 2, seg = t & 3;
        float frA[8], frB[8];
        #pragma unroll
        for (int i = 0; i < 8; ++i) {
            frA[i] = exp2f(-(float)(seg*8 + i)      * 0.2076205059304601f);
            frB[i] = exp2f(-(float)(32 + seg*8 + i) * 0.2076205059304601f);
        }
        const float f0 = PF[er][3], f1 = PF[er][4], f2 = PF[er][5];
        const int slotbase = (er>>4)*12*64 + seg*16 + (er&15);
        #pragma unroll
        for (int blk = 0; blk < 12; ++blk) {
            const float pc = PF[er][blk>>2];
            float v[8];
            #pragma unroll
            for (int i = 0; i < 8; ++i) {
                const int dim = blk*32 + seg*8 + i;
                const float fr = (blk & 1) ? frB[i] : frA[i];
                const float a  = pc * fr;
                const float base = ((blk>>1) & 1) ? __cosf(a) : __sinf(a);
                const float4 wv = *(const float4*)WINT[dim];
                v[i] = fmaf(f0, wv.x, fmaf(f1, wv.y, fmaf(f2, wv.z, base + wv.w)));
            }
            *(bf16x8*)&G[(size_t)(slotbase + blk*64)*8] = pack8(v);
        }
    }
    __syncthreads();

    const int l = t & 63, ng = t >> 6, lg = l >> 4, l15 = l & 15;

    f32x4 acc[4][6];
    bf16x8 bA[6], bB[6];

    #define LOADB(dst, Wf, kt)                                                  \
        { const unsigned short* bp_ = &Wf[((size_t)((kt)*24 + ng*6)*64 + l)*8]; \
          _Pragma("unroll")                                                     \
          for (int nt_ = 0; nt_ < 6; ++nt_)                                     \
              dst[nt_] = *(const bf16x8*)(bp_ + (size_t)nt_*512); }
    #define AREAD(a_, kt)                                                       \
        { _Pragma("unroll")                                                     \
          for (int mt_ = 0; mt_ < 4; ++mt_)                                     \
              a_[mt_] = *(const bf16x8*)&G[(size_t)(((mt_*12 + (kt))*64) + l)*8]; }
    #define MFMA6(bfr, a_)                                                      \
        { _Pragma("unroll")                                                     \
          for (int mt_ = 0; mt_ < 4; ++mt_)                                     \
              _Pragma("unroll")                                                 \
              for (int nt_ = 0; nt_ < 6; ++nt_)                                 \
                  acc[mt_][nt_] = __builtin_amdgcn_mfma_f32_16x16x32_bf16(      \
                      a_[mt_], bfr[nt_], acc[mt_][nt_], 0, 0, 0); }

    // ---- layer 1: Y1 = E @ W1src, B double-buffered ----
    #pragma unroll
    for (int mt=0; mt<4; ++mt)
        #pragma unroll
        for (int nt=0; nt<6; ++nt) acc[mt][nt] = (f32x4){0.f,0.f,0.f,0.f};
    LOADB(bA, W1f, 0); LOADB(bB, W1f, 1);
    #pragma unroll
    for (int kt = 0; kt < 12; kt += 2) {
        bf16x8 a[4];
        AREAD(a, kt);
        MFMA6(bA, a);
        if (kt + 2 < 12) LOADB(bA, W1f, kt + 2);
        AREAD(a, kt + 1);
        MFMA6(bB, a);
        if (kt + 3 < 12) LOADB(bB, W1f, kt + 3);
    }
    __syncthreads();   // all G reads done

    // ---- gelu epilogue: scatter bf16 into frag-major G for layer 2 ----
    #pragma unroll
    for (int mt=0; mt<4; ++mt) {
        const int sl = mt >> 1;   // supernode slot (rows 0..31 vs 32..63)
        #pragma unroll
        for (int nt=0; nt<6; ++nt) {
            const int col = ng*96 + nt*16 + l15;
            const float dv = DSTV[sl][col];
            const int base = ((mt*12 + (col>>5))*64 + ((col>>3)&3)*16 + lg*4)*8 + (col&7);
            #pragma unroll
            for (int r=0; r<4; ++r)
                G[base + r*8] = f2bf(gelu(acc[mt][nt][r] + dv));
        }
    }
    __syncthreads();

    // ---- layer 2: Y2 = G @ W2 ----
    #pragma unroll
    for (int mt=0; mt<4; ++mt)
        #pragma unroll
        for (int nt=0; nt<6; ++nt) acc[mt][nt] = (f32x4){0.f,0.f,0.f,0.f};
    LOADB(bA, W2f, 0); LOADB(bB, W2f, 1);
    #pragma unroll
    for (int kt = 0; kt < 12; kt += 2) {
        bf16x8 a[4];
        AREAD(a, kt);
        MFMA6(bA, a);
        if (kt + 2 < 12) LOADB(bA, W2f, kt + 2);
        AREAD(a, kt + 1);
        MFMA6(bB, a);
        if (kt + 3 < 12) LOADB(bB, W2f, kt + 3);
    }

    // ---- masked mean -> aggb (bf16, b2 folded) ----
    #pragma unroll
    for (int nt=0; nt<6; ++nt) {
        const int col = ng*96 + nt*16 + l15;
        float s0 = 0.f, s1 = 0.f;
        #pragma unroll
        for (int mt=0; mt<4; ++mt) {
            float p = 0.f;
            #pragma unroll
            for (int r=0; r<4; ++r)
                p += PF[mt*16 + lg*4 + r][6] * acc[mt][nt][r];
            if (mt < 2) s0 += p; else s1 += p;
        }
        s0 += __shfl_xor(s0,16); s0 += __shfl_xor(s0,32);
        s1 += __shfl_xor(s1,16); s1 += __shfl_xor(s1,32);
        if (lg == 0) {
            const float bb = b2[col];
            const int sn0 = bm*2;
            const float c0 = CNT[0], c1 = CNT[1];
            aggb[(size_t)sn0*HIDDEN + col]     = f2bf(s0 / fmaxf(c0,1.f) + bb*(c0>0.f?1.f:0.f));
            aggb[(size_t)(sn0+1)*HIDDEN + col] = f2bf(s1 / fmaxf(c1,1.f) + bb*(c1>0.f?1.f:0.f));
        }
    }
    #undef LOADB
    #undef AREAD
    #undef MFMA6
}

// ---- projection: out = [aggb|snxb] @ Wp + bp.  128 blocks = 32 rg x 4 cq ----
__global__ __launch_bounds__(256)
void k_proj(const unsigned short* __restrict__ aggb,
            const unsigned short* __restrict__ snxb,
            const unsigned short* __restrict__ wpf,
            const float* __restrict__ bp, float* __restrict__ out) {
    const int rg = blockIdx.x >> 2, cq = blockIdx.x & 3;
    const int t = threadIdx.x, w = t>>6, l = t&63, lg = l>>4, l15 = l&15;
    const int wgm = w>>1, wgn = w&1;
    const int r0 = rg*64 + wgm*32;
    const int ntb = cq*6 + wgn*3;
    f32x4 acc[2][3];
    #pragma unroll
    for (int mt=0; mt<2; ++mt)
        #pragma unroll
        for (int nt=0; nt<3; ++nt) acc[mt][nt] = (f32x4){0.f,0.f,0.f,0.f};
    #pragma unroll 2
    for (int kt = 0; kt < 24; ++kt) {
        const unsigned short* Ab = (kt < 12) ? aggb : snxb;
        const unsigned short* Wb = (kt < 12) ? wpf  : wpf + WBLK;
        const int ktt = (kt < 12) ? kt : kt - 12;
        bf16x8 a[2], bfr[3];
        const unsigned short* bpp = &Wb[((size_t)(ktt*24 + ntb)*64 + l)*8];
        #pragma unroll
        for (int nt=0; nt<3; ++nt) bfr[nt] = *(const bf16x8*)(bpp + (size_t)nt*512);
        #pragma unroll
        for (int mt=0; mt<2; ++mt)
            a[mt] = *(const bf16x8*)&Ab[(size_t)(r0 + mt*16 + l15)*HIDDEN + ktt*32 + lg*8];
        #pragma unroll
        for (int mt=0; mt<2; ++mt)
            #pragma unroll
            for (int nt=0; nt<3; ++nt)
                acc[mt][nt] = __builtin_amdgcn_mfma_f32_16x16x32_bf16(a[mt], bfr[nt], acc[mt][nt], 0,0,0);
    }
    #pragma unroll
    for (int mt=0; mt<2; ++mt)
        #pragma unroll
        for (int nt=0; nt<3; ++nt) {
            const int col = cq*96 + wgn*48 + nt*16 + l15;
            #pragma unroll
            for (int r=0; r<4; ++r) {
                const int row = r0 + mt*16 + lg*4 + r;
                out[(size_t)row*HIDDEN + col] = acc[mt][nt][r] + bp[col];
            }
        }
}

extern "C" void kernel_launch(void* const* d_in, const int* in_sizes, int n_in,
                              void* d_out, int out_size, void* d_ws, size_t ws_size,
                              hipStream_t stream) {
    const float* pos   = (const float*)d_in[0];
    const float* feat  = (const float*)d_in[1];
    const int*   sn    = (const int*)d_in[2];
    const int*   nbr   = (const int*)d_in[3];
    const void*  mask  = d_in[4];
    const float* W_in  = (const float*)d_in[5];
    const float* b_in  = (const float*)d_in[6];
    const float* W1    = (const float*)d_in[7];
    const float* b1    = (const float*)d_in[8];
    const float* W2    = (const float*)d_in[9];
    const float* b2    = (const float*)d_in[10];
    const float* Wp    = (const float*)d_in[11];
    const float* bpv   = (const float*)d_in[12];
    float* out = (float*)d_out;

    char* base = (char*)d_ws;
    int* flag = (int*)base;
    unsigned short* w1sf = (unsigned short*)(base + 256);
    unsigned short* w1df = w1sf + WBLK;
    unsigned short* w2f  = w1df + WBLK;
    unsigned short* wpf  = w2f  + WBLK;                  // 2 blocks (768 rows)
    unsigned short* snxb = wpf  + 2*(size_t)WBLK;        // 2048*384 bf16
    unsigned short* aggb = snxb + (size_t)NSUPER*HIDDEN;
    float* dstv = (float*)(aggb + (size_t)NSUPER*HIDDEN); // 2048*384 f32

    hipLaunchKernelGGL(prep, dim3(361), dim3(256), 0, stream,
                       W1, W2, Wp, (const unsigned int*)mask, w1sf, w1df, w2f, wpf, flag);
    hipLaunchKernelGGL(k_embdst, dim3(64), dim3(256), 0, stream,
                       pos, feat, sn, W_in, b_in, w1df, b1, snxb, dstv);
    hipLaunchKernelGGL(k_mlp, dim3(1024), dim3(256), 0, stream,
                       pos, feat, nbr, mask, flag, W_in, b_in, dstv, w1sf, w2f, b2, aggb);
    hipLaunchKernelGGL(k_proj, dim3(128), dim3(256), 0, stream,
                       aggb, snxb, wpf, bpv, out);
}